// Round 2
// baseline (296.466 us; speedup 1.0000x reference)
//
#include <hip/hip_runtime.h>
#include <math.h>

#define B 256
#define C 1000
#define D 128
#define QN 262144

// output layout (floats):
// [0]        output        B*C      = 256000
// [256000]   output2       B*C      = 256000
// [512000]   features      (2B+Q)*D = 33619968
// [34131968] pseudo_labels (2B+Q)   = 262656
// [34394624] score_prot    B*C      = 256000
// [34650624] protos        C*D      = 128000
#define OFF_FEAT   512000
#define OFF_LBL    34131968
#define OFF_SCORE  34394624
#define OFF_PROTO  34650624

// ---- fused copy segment geometry, in float4 units ----
#define N_Q4   (QN * D / 4)          /* 8388608  queue -> features[2B:]   */
#define N_O4   (B * C / 4)           /* 64000    output / output2         */
#define N_F4   (B * D / 4)           /* 8192     q / k -> features[:2B]   */
#define N_P4   (QN / 4)              /* 65536    queue_pseudo             */
#define TOT4   (N_Q4 + 2 * N_O4 + 2 * N_F4 + N_P4)   /* 8598336 */

#define DST_Q4   ((OFF_FEAT + 2 * B * D) / 4)
#define DST_O14  0
#define DST_O24  (B * C / 4)
#define DST_QF4  (OFF_FEAT / 4)
#define DST_KF4  (OFF_FEAT / 4 + N_F4)
#define DST_P4   ((OFF_LBL + 2 * B) / 4)

// ---------------- fused bulk copy (compute-engine, float4) ----------------------
__global__ __launch_bounds__(256) void copy_kernel(
    const float4* __restrict__ q,
    const float4* __restrict__ k,
    const float4* __restrict__ output,
    const float4* __restrict__ output2,
    const float4* __restrict__ queue,
    const float4* __restrict__ queue_pseudo,
    float4* __restrict__ out4)
{
    size_t i = (size_t)blockIdx.x * blockDim.x + threadIdx.x;
    const size_t stride = (size_t)gridDim.x * blockDim.x;
    for (; i < TOT4; i += stride) {
        // queue segment first: it is 97.6% of the traffic
        if (i < N_Q4) {
            out4[DST_Q4 + i] = queue[i];
        } else if (i < N_Q4 + N_O4) {
            size_t j = i - N_Q4;
            out4[DST_O14 + j] = output[j];
        } else if (i < N_Q4 + 2 * N_O4) {
            size_t j = i - N_Q4 - N_O4;
            out4[DST_O24 + j] = output2[j];
        } else if (i < N_Q4 + 2 * N_O4 + N_F4) {
            size_t j = i - N_Q4 - 2 * N_O4;
            out4[DST_QF4 + j] = q[j];
        } else if (i < N_Q4 + 2 * N_O4 + 2 * N_F4) {
            size_t j = i - N_Q4 - 2 * N_O4 - N_F4;
            out4[DST_KF4 + j] = k[j];
        } else {
            size_t j = i - N_Q4 - 2 * N_O4 - 2 * N_F4;
            out4[DST_P4 + j] = queue_pseudo[j];
        }
    }
}

// ---------------- argmax of output*partial_Y per row (first-occurrence ties) ----
__global__ __launch_bounds__(256) void argmax_kernel(
    const float* __restrict__ output,
    const float* __restrict__ partial_Y,
    int* __restrict__ labels,
    float* __restrict__ out_labels)   // d_out + OFF_LBL
{
    const int b = blockIdx.x;
    const int tid = threadIdx.x;
    const float* row = output + (size_t)b * C;
    const float* msk = partial_Y + (size_t)b * C;

    float best = -INFINITY;
    int bidx = C;  // sentinel, always replaced
    for (int c = tid; c < C; c += 256) {
        float v = row[c] * msk[c];
        if (v > best) { best = v; bidx = c; }  // strict > keeps first occurrence
    }

    __shared__ float sv[256];
    __shared__ int   si[256];
    sv[tid] = best; si[tid] = bidx;
    __syncthreads();
    for (int s = 128; s > 0; s >>= 1) {
        if (tid < s) {
            float v2 = sv[tid + s]; int i2 = si[tid + s];
            if (v2 > sv[tid] || (v2 == sv[tid] && i2 < si[tid])) {
                sv[tid] = v2; si[tid] = i2;
            }
        }
        __syncthreads();
    }
    if (tid == 0) {
        int lab = si[0];
        labels[b] = lab;
        float f = (float)lab;
        out_labels[b]     = f;
        out_labels[B + b] = f;
    }
}

// ---------------- score_prot = softmax(q @ P^T) per row -------------------------
__global__ __launch_bounds__(256) void scoreprot_kernel(
    const float* __restrict__ q,
    const float* __restrict__ protos,
    float* __restrict__ out)          // d_out + OFF_SCORE
{
    const int b = blockIdx.x;
    const int tid = threadIdx.x;

    __shared__ float qs[D];
    if (tid < D) qs[tid] = q[(size_t)b * D + tid];
    __syncthreads();

    __shared__ float logits[C];
    for (int c = tid; c < C; c += 256) {
        const float4* p4 = (const float4*)(protos + (size_t)c * D);
        const float4* q4 = (const float4*)qs;
        float acc = 0.f;
        #pragma unroll
        for (int d = 0; d < D / 4; ++d) {
            float4 pv = p4[d];
            float4 qv = q4[d];
            acc += pv.x * qv.x + pv.y * qv.y + pv.z * qv.z + pv.w * qv.w;
        }
        logits[c] = acc;
    }
    __syncthreads();

    __shared__ float red[256];
    float lm = -INFINITY;
    for (int c = tid; c < C; c += 256) lm = fmaxf(lm, logits[c]);
    red[tid] = lm;
    __syncthreads();
    for (int s = 128; s > 0; s >>= 1) {
        if (tid < s) red[tid] = fmaxf(red[tid], red[tid + s]);
        __syncthreads();
    }
    const float m = red[0];
    __syncthreads();

    float psum = 0.f;
    for (int c = tid; c < C; c += 256) {
        float e = expf(logits[c] - m);
        logits[c] = e;
        psum += e;
    }
    red[tid] = psum;
    __syncthreads();
    for (int s = 128; s > 0; s >>= 1) {
        if (tid < s) red[tid] += red[tid + s];
        __syncthreads();
    }
    const float denom = red[0];

    for (int c = tid; c < C; c += 256)
        out[(size_t)b * C + c] = logits[c] / denom;
}

// ---------------- EMA scatter (sequential-in-b per class) + L2 normalize --------
__global__ __launch_bounds__(128) void ema_kernel(
    const float* __restrict__ q,
    const float* __restrict__ protos_in,
    const int* __restrict__ labels,
    float* __restrict__ out)          // d_out + OFF_PROTO
{
    const int c = blockIdx.x;    // class row
    const int d = threadIdx.x;   // dim

    __shared__ int lab[B];
    for (int i = d; i < B; i += 128) lab[i] = labels[i];
    __syncthreads();

    float val = protos_in[(size_t)c * D + d];
    for (int b = 0; b < B; ++b) {
        if (lab[b] == c) {                       // block-uniform branch
            val = val * 0.99f + 0.01f * q[(size_t)b * D + d];
        }
    }

    __shared__ float ss[128];
    ss[d] = val * val;
    __syncthreads();
    for (int s = 64; s > 0; s >>= 1) {
        if (d < s) ss[d] += ss[d + s];
        __syncthreads();
    }
    float r = fmaxf(sqrtf(ss[0]), 1e-12f);
    out[(size_t)c * D + d] = val / r;
}

extern "C" void kernel_launch(void* const* d_in, const int* in_sizes, int n_in,
                              void* d_out, int out_size, void* d_ws, size_t ws_size,
                              hipStream_t stream) {
    const float* q            = (const float*)d_in[0];
    const float* k            = (const float*)d_in[1];
    const float* output       = (const float*)d_in[2];
    const float* output2      = (const float*)d_in[3];
    const float* partial_Y    = (const float*)d_in[4];
    const float* prototypes   = (const float*)d_in[5];
    const float* queue        = (const float*)d_in[6];
    const float* queue_pseudo = (const float*)d_in[7];

    float* out = (float*)d_out;
    int* labels = (int*)d_ws;

    // small compute kernels first (labels -> ema dependency; same stream serializes)
    argmax_kernel<<<B, 256, 0, stream>>>(output, partial_Y, labels, out + OFF_LBL);
    ema_kernel<<<C, 128, 0, stream>>>(q, prototypes, labels, out + OFF_PROTO);
    scoreprot_kernel<<<B, 256, 0, stream>>>(q, prototypes, out + OFF_SCORE);

    // one fused compute-engine copy for all bulk traffic (~275 MB total)
    // grid: 2048 wg x 256 thr = 524288 threads, ~16.4 float4/thread grid-stride
    copy_kernel<<<2048, 256, 0, stream>>>(
        (const float4*)q, (const float4*)k,
        (const float4*)output, (const float4*)output2,
        (const float4*)queue, (const float4*)queue_pseudo,
        (float4*)out);
}

// Round 3
// 291.305 us; speedup vs baseline: 1.0177x; 1.0177x over previous
//
#include <hip/hip_runtime.h>
#include <math.h>

#define B 256
#define C 1000
#define D 128
#define QN 262144

// output layout (floats):
// [0]        output        B*C      = 256000
// [256000]   output2       B*C      = 256000
// [512000]   features      (2B+Q)*D = 33619968
// [34131968] pseudo_labels (2B+Q)   = 262656
// [34394624] score_prot    B*C      = 256000
// [34650624] protos        C*D      = 128000
#define OFF_FEAT   512000
#define OFF_LBL    34131968
#define OFF_SCORE  34394624
#define OFF_PROTO  34650624

#define N_Q4   (QN * D / 4)          /* 8388608 float4: queue -> features[2B:] */
#define N_O4   (B * C / 4)           /* 64000 */
#define N_F4   (B * D / 4)           /* 8192  */
#define N_P4   (QN / 4)              /* 65536 */

#define DST_Q4   ((OFF_FEAT + 2 * B * D) / 4)
#define DST_O24  (B * C / 4)
#define DST_QF4  (OFF_FEAT / 4)
#define DST_KF4  (OFF_FEAT / 4 + N_F4)
#define DST_P4   ((OFF_LBL + 2 * B) / 4)

// ---------------- queue copy: 4 independent float4 per thread -------------------
// block covers 1024 contiguous float4 (16 KB); 4 loads in flight per thread.
__global__ __launch_bounds__(256) void copyq_kernel(
    const float4* __restrict__ src, float4* __restrict__ dst)
{
    const size_t base = (size_t)blockIdx.x * 1024 + threadIdx.x;
    float4 a = src[base];
    float4 b = src[base + 256];
    float4 c = src[base + 512];
    float4 d = src[base + 768];
    dst[base]       = a;
    dst[base + 256] = b;
    dst[base + 512] = c;
    dst[base + 768] = d;
}

// ---------------- small segments (~3.3 MB total): branchy is fine ---------------
#define SM_O2  (N_O4)                         /* after: output2 */
#define SM_Q   (2 * N_O4)                     /* after: q       */
#define SM_K   (2 * N_O4 + N_F4)              /* after: k       */
#define SM_P   (2 * N_O4 + 2 * N_F4)          /* after: pseudo  */
#define SM_TOT (2 * N_O4 + 2 * N_F4 + N_P4)   /* 209920 float4  */

__global__ __launch_bounds__(256) void copysmall_kernel(
    const float4* __restrict__ q,
    const float4* __restrict__ k,
    const float4* __restrict__ output,
    const float4* __restrict__ output2,
    const float4* __restrict__ queue_pseudo,
    float4* __restrict__ out4)
{
    size_t i = (size_t)blockIdx.x * blockDim.x + threadIdx.x;
    if (i >= SM_TOT) return;
    if (i < SM_O2)       out4[i]                    = output[i];
    else if (i < SM_Q)   out4[DST_O24 + (i - SM_O2)] = output2[i - SM_O2];
    else if (i < SM_K)   out4[DST_QF4 + (i - SM_Q)]  = q[i - SM_Q];
    else if (i < SM_P)   out4[DST_KF4 + (i - SM_K)]  = k[i - SM_K];
    else                 out4[DST_P4 + (i - SM_P)]   = queue_pseudo[i - SM_P];
}

// ---------------- argmax of output*partial_Y per row (first-occurrence ties) ----
__global__ __launch_bounds__(256) void argmax_kernel(
    const float* __restrict__ output,
    const float* __restrict__ partial_Y,
    int* __restrict__ labels,
    float* __restrict__ out_labels)   // d_out + OFF_LBL
{
    const int b = blockIdx.x;
    const int tid = threadIdx.x;
    const float* row = output + (size_t)b * C;
    const float* msk = partial_Y + (size_t)b * C;

    float best = -INFINITY;
    int bidx = C;
    for (int c = tid; c < C; c += 256) {
        float v = row[c] * msk[c];
        if (v > best) { best = v; bidx = c; }  // strict > keeps first occurrence
    }

    __shared__ float sv[256];
    __shared__ int   si[256];
    sv[tid] = best; si[tid] = bidx;
    __syncthreads();
    for (int s = 128; s > 0; s >>= 1) {
        if (tid < s) {
            float v2 = sv[tid + s]; int i2 = si[tid + s];
            if (v2 > sv[tid] || (v2 == sv[tid] && i2 < si[tid])) {
                sv[tid] = v2; si[tid] = i2;
            }
        }
        __syncthreads();
    }
    if (tid == 0) {
        int lab = si[0];
        labels[b] = lab;
        float f = (float)lab;
        out_labels[b]     = f;
        out_labels[B + b] = f;
    }
}

// ---------------- score_prot = softmax(q @ P^T) per row -------------------------
__global__ __launch_bounds__(256) void scoreprot_kernel(
    const float* __restrict__ q,
    const float* __restrict__ protos,
    float* __restrict__ out)          // d_out + OFF_SCORE
{
    const int b = blockIdx.x;
    const int tid = threadIdx.x;

    __shared__ float qs[D];
    if (tid < D) qs[tid] = q[(size_t)b * D + tid];
    __syncthreads();

    __shared__ float logits[C];
    for (int c = tid; c < C; c += 256) {
        const float4* p4 = (const float4*)(protos + (size_t)c * D);
        const float4* q4 = (const float4*)qs;
        float acc = 0.f;
        #pragma unroll
        for (int d = 0; d < D / 4; ++d) {
            float4 pv = p4[d];
            float4 qv = q4[d];
            acc += pv.x * qv.x + pv.y * qv.y + pv.z * qv.z + pv.w * qv.w;
        }
        logits[c] = acc;
    }
    __syncthreads();

    __shared__ float red[256];
    float lm = -INFINITY;
    for (int c = tid; c < C; c += 256) lm = fmaxf(lm, logits[c]);
    red[tid] = lm;
    __syncthreads();
    for (int s = 128; s > 0; s >>= 1) {
        if (tid < s) red[tid] = fmaxf(red[tid], red[tid + s]);
        __syncthreads();
    }
    const float m = red[0];
    __syncthreads();

    float psum = 0.f;
    for (int c = tid; c < C; c += 256) {
        float e = expf(logits[c] - m);
        logits[c] = e;
        psum += e;
    }
    red[tid] = psum;
    __syncthreads();
    for (int s = 128; s > 0; s >>= 1) {
        if (tid < s) red[tid] += red[tid + s];
        __syncthreads();
    }
    const float denom = red[0];

    for (int c = tid; c < C; c += 256)
        out[(size_t)b * C + c] = logits[c] / denom;
}

// ---------------- EMA scatter (sequential-in-b per class) + L2 normalize --------
__global__ __launch_bounds__(128) void ema_kernel(
    const float* __restrict__ q,
    const float* __restrict__ protos_in,
    const int* __restrict__ labels,
    float* __restrict__ out)          // d_out + OFF_PROTO
{
    const int c = blockIdx.x;    // class row
    const int d = threadIdx.x;   // dim

    __shared__ int lab[B];
    for (int i = d; i < B; i += 128) lab[i] = labels[i];
    __syncthreads();

    float val = protos_in[(size_t)c * D + d];
    for (int b = 0; b < B; ++b) {
        if (lab[b] == c) {                       // block-uniform branch
            val = val * 0.99f + 0.01f * q[(size_t)b * D + d];
        }
    }

    __shared__ float ss[128];
    ss[d] = val * val;
    __syncthreads();
    for (int s = 64; s > 0; s >>= 1) {
        if (d < s) ss[d] += ss[d + s];
        __syncthreads();
    }
    float r = fmaxf(sqrtf(ss[0]), 1e-12f);
    out[(size_t)c * D + d] = val / r;
}

extern "C" void kernel_launch(void* const* d_in, const int* in_sizes, int n_in,
                              void* d_out, int out_size, void* d_ws, size_t ws_size,
                              hipStream_t stream) {
    const float* q            = (const float*)d_in[0];
    const float* k            = (const float*)d_in[1];
    const float* output       = (const float*)d_in[2];
    const float* output2      = (const float*)d_in[3];
    const float* partial_Y    = (const float*)d_in[4];
    const float* prototypes   = (const float*)d_in[5];
    const float* queue        = (const float*)d_in[6];
    const float* queue_pseudo = (const float*)d_in[7];

    float* out = (float*)d_out;
    int* labels = (int*)d_ws;

    // small compute kernels (labels -> ema dependency; same stream serializes)
    argmax_kernel<<<B, 256, 0, stream>>>(output, partial_Y, labels, out + OFF_LBL);
    ema_kernel<<<C, 128, 0, stream>>>(q, prototypes, labels, out + OFF_PROTO);
    scoreprot_kernel<<<B, 256, 0, stream>>>(q, prototypes, out + OFF_SCORE);

    // bulk queue copy: 8388608 float4 / 1024 per block = 8192 blocks exactly
    copyq_kernel<<<N_Q4 / 1024, 256, 0, stream>>>(
        (const float4*)queue, (float4*)out + DST_Q4);

    // small segments: 209920 float4, 1 per thread
    copysmall_kernel<<<(SM_TOT + 255) / 256, 256, 0, stream>>>(
        (const float4*)q, (const float4*)k,
        (const float4*)output, (const float4*)output2,
        (const float4*)queue_pseudo, (float4*)out);
}